// Round 7
// baseline (68.181 us; speedup 1.0000x reference)
//
#include <hip/hip_runtime.h>

// SeeSawLoss, simplified:
//   loss(b,h,w) = log( sum_i exp(l[b,i,h,w]) * max(w[b,i], w[b,t]) ) - log(w[b,t]) - l[b,t,h,w]
//   out = mean over all (b,h,w);  M[i,t] = (wi>wt ? wi/wt : 1) == max(wi,wt)/wt
// B=8, N=128, H=W=128.
//
// Single fused dispatch. R6 failed with relaxed-store/acquire-load partials
// (per-XCD writeback L2 staleness, Guideline 16). Fix: all cross-workgroup
// communication via device-coherent RMWs (atomicExch to publish, atomicAdd(+0)
// to read), as in R4's validated finale. Monotonic counter (old & 2047) fires
// exactly once per call for any initial value -> no ws reset, poison-proof.
// Fixed-order finisher sum -> bitwise deterministic.

#define B_    8
#define N_    128
#define HW_   16384              // 128*128
#define NPIX  (B_ * HW_)         // 131072
#define BLOCK 256
#define PX    64                 // pixels per block
#define OCTS  8                  // class octants
#define CPT   16                 // classes per thread
#define BLOCKS_PER_B (HW_ / PX)  // 256
#define NBLOCKS (B_ * BLOCKS_PER_B)  // 2048

__global__ __launch_bounds__(BLOCK) void seesaw_fused(
    const float* __restrict__ logit,
    const int*   __restrict__ target,
    const float* __restrict__ weight,
    float*        partials,          // ws[0 .. 2047], published via atomicExch
    unsigned int* cnt,               // own cache line, monotonic
    float*        out)
{
    __shared__ float w_s[N_];
    __shared__ float sa[OCTS][PX];
    __shared__ int   t_s[PX];
    __shared__ float red[4];
    __shared__ int   is_last;

    const int tid  = threadIdx.x;
    const int b    = blockIdx.x >> 8;            // / BLOCKS_PER_B
    const int pix0 = (blockIdx.x & 255) * PX;
    const int pp   = tid & 31;                   // pixel-pair index
    const int q    = tid >> 5;                   // class octant
    const int px   = pp * 2;

    if (tid < N_) w_s[tid] = weight[b * N_ + tid];
    __syncthreads();

    const int2 t2 = *(const int2*)(target + b * HW_ + pix0 + px);
    if (q == 0) *(int2*)&t_s[px] = t2;

    const float wt0 = w_s[t2.x];
    const float wt1 = w_s[t2.y];

    const int ibase = q * CPT;
    const float* lp = logit + (size_t)(b * N_ + ibase) * HW_ + pix0 + px;

    float a0 = 0.0f, a1 = 0.0f;

    #pragma unroll
    for (int k = 0; k < CPT; ++k) {
        const float2 l = *(const float2*)(lp + (size_t)k * HW_);
        const float wi = w_s[ibase + k];
        a0 = fmaf(__expf(l.x), fmaxf(wi, wt0), a0);
        a1 = fmaf(__expf(l.y), fmaxf(wi, wt1), a1);
    }

    *(float2*)&sa[q][px] = make_float2(a0, a1);
    __syncthreads();

    float loss = 0.0f;
    if (tid < PX) {                              // wave 0: one lane per pixel
        float at = 0.0f;
        #pragma unroll
        for (int k = 0; k < OCTS; ++k) at += sa[k][tid];
        const int   t  = t_s[tid];
        const float wt = w_s[t];
        const float lt = logit[(size_t)(b * N_ + t) * HW_ + pix0 + tid];  // cache-warm
        loss = __logf(at) - __logf(wt) - lt;

        #pragma unroll
        for (int o = 32; o > 0; o >>= 1) loss += __shfl_down(loss, o, 64);
    }

    if (tid == 0) {
        atomicExch(&partials[blockIdx.x], loss);     // device-coherent publish
        __threadfence();
        const unsigned int old = atomicAdd(cnt, 1u); // monotonic
        is_last = ((old & (NBLOCKS - 1)) == (NBLOCKS - 1)) ? 1 : 0;
    }
    __syncthreads();

    if (is_last) {                               // exactly one block per call
        __threadfence();
        float s = 0.0f;
        #pragma unroll
        for (int i = 0; i < NBLOCKS / BLOCK; ++i)    // fixed order -> deterministic
            s += atomicAdd(&partials[i * BLOCK + tid], 0.0f);  // coherent RMW read
        #pragma unroll
        for (int o = 32; o > 0; o >>= 1) s += __shfl_down(s, o, 64);
        if ((tid & 63) == 0) red[tid >> 6] = s;
        __syncthreads();
        if (tid == 0)
            out[0] = (red[0] + red[1] + red[2] + red[3]) * (1.0f / (float)NPIX);
    }
}

extern "C" void kernel_launch(void* const* d_in, const int* in_sizes, int n_in,
                              void* d_out, int out_size, void* d_ws, size_t ws_size,
                              hipStream_t stream)
{
    const float* logit  = (const float*)d_in[0];
    const int*   target = (const int*)  d_in[1];
    const float* weight = (const float*)d_in[2];
    // d_in[3] = epoch (unused by the reference math)

    float*        partials = (float*)d_ws;                        // 8192 B
    unsigned int* cnt      = (unsigned int*)((char*)d_ws + 8320); // own line
    float*        out      = (float*)d_out;

    seesaw_fused<<<NBLOCKS, BLOCK, 0, stream>>>(logit, target, weight,
                                                partials, cnt, out);
}

// Round 8
// 19.157 us; speedup vs baseline: 3.5591x; 3.5591x over previous
//
#include <hip/hip_runtime.h>

// SeeSawLoss, simplified:
//   loss(b,h,w) = log( sum_i exp(l[b,i,h,w]) * max(w[b,i], w[b,t]) ) - log(w[b,t]) - l[b,t,h,w]
//   out = mean over all (b,h,w);  M[i,t] = (wi>wt ? wi/wt : 1) == max(wi,wt)/wt
// B=8, N=128, H=W=128.
//
// Model (R5/R7 evidence): with >=16 waves/CU the main loop is VMEM-issue
// bound (~1 VMEM instr/cycle/CU). R5 float2 = 32768 instr/CU = 13.7us.
// This round: float4 halves that. Two-kernel reduction (R7 proved fused
// atomic epilogue costs ~50us; a second dispatch is ~2-3us).

#define B_    8
#define N_    128
#define HW_   16384              // 128*128
#define NPIX  (B_ * HW_)         // 131072
#define BLOCK 256
#define PX    128                // pixels per block
#define OCTS  8                  // class octants
#define CPT   16                 // classes per thread
#define BLOCKS_PER_B (HW_ / PX)  // 128
#define NBLOCKS (B_ * BLOCKS_PER_B)  // 1024

__global__ __launch_bounds__(BLOCK) void seesaw_main(
    const float* __restrict__ logit,
    const int*   __restrict__ target,
    const float* __restrict__ weight,
    float*       __restrict__ partials)
{
    __shared__ float w_s[N_];
    __shared__ float sa[OCTS][PX];
    __shared__ int   t_s[PX];
    __shared__ float red[4];

    const int tid  = threadIdx.x;
    const int b    = blockIdx.x >> 7;             // / BLOCKS_PER_B
    const int pix0 = (blockIdx.x & 127) * PX;
    const int quad = (tid & 31) * 4;              // 4 consecutive pixels
    const int q    = tid >> 5;                    // class octant

    if (tid < N_) w_s[tid] = weight[b * N_ + tid];
    __syncthreads();

    const int4 t4 = *(const int4*)(target + b * HW_ + pix0 + quad);
    if (q == 0) *(int4*)&t_s[quad] = t4;

    const float wt0 = w_s[t4.x], wt1 = w_s[t4.y], wt2 = w_s[t4.z], wt3 = w_s[t4.w];

    const int ibase = q * CPT;
    const float* lp = logit + (size_t)(b * N_ + ibase) * HW_ + pix0 + quad;

    float a0 = 0.f, a1 = 0.f, a2 = 0.f, a3 = 0.f;

    #pragma unroll
    for (int k = 0; k < CPT; ++k) {
        const float4 l = *(const float4*)(lp + (size_t)k * HW_);
        const float wi = w_s[ibase + k];
        a0 = fmaf(__expf(l.x), fmaxf(wi, wt0), a0);
        a1 = fmaf(__expf(l.y), fmaxf(wi, wt1), a1);
        a2 = fmaf(__expf(l.z), fmaxf(wi, wt2), a2);
        a3 = fmaf(__expf(l.w), fmaxf(wi, wt3), a3);
    }

    *(float4*)&sa[q][quad] = make_float4(a0, a1, a2, a3);
    __syncthreads();

    float loss = 0.0f;
    if (tid < PX) {                              // waves 0,1: one lane per pixel
        float at = 0.0f;
        #pragma unroll
        for (int k = 0; k < OCTS; ++k) at += sa[k][tid];
        const int   t  = t_s[tid];
        const float wt = w_s[t];
        const float lt = logit[(size_t)(b * N_ + t) * HW_ + pix0 + tid];  // cache-warm
        loss = __logf(at) - __logf(wt) - lt;
    }

    #pragma unroll
    for (int o = 32; o > 0; o >>= 1) loss += __shfl_down(loss, o, 64);
    if ((tid & 63) == 0) red[tid >> 6] = loss;
    __syncthreads();

    if (tid == 0) partials[blockIdx.x] = red[0] + red[1] + red[2] + red[3];
}

__global__ __launch_bounds__(1024) void seesaw_reduce(
    const float* __restrict__ partials,
    float*       __restrict__ out)
{
    __shared__ float red[16];
    float s = partials[threadIdx.x];

    #pragma unroll
    for (int o = 32; o > 0; o >>= 1) s += __shfl_down(s, o, 64);

    const int lane = threadIdx.x & 63;
    const int wid  = threadIdx.x >> 6;
    if (lane == 0) red[wid] = s;
    __syncthreads();

    if (threadIdx.x == 0) {
        float tot = 0.0f;
        #pragma unroll
        for (int k = 0; k < 16; ++k) tot += red[k];
        out[0] = tot * (1.0f / (float)NPIX);
    }
}

extern "C" void kernel_launch(void* const* d_in, const int* in_sizes, int n_in,
                              void* d_out, int out_size, void* d_ws, size_t ws_size,
                              hipStream_t stream)
{
    const float* logit  = (const float*)d_in[0];
    const int*   target = (const int*)  d_in[1];
    const float* weight = (const float*)d_in[2];
    // d_in[3] = epoch (unused by the reference math)

    float* partials = (float*)d_ws;   // NBLOCKS floats
    float* out      = (float*)d_out;

    seesaw_main<<<NBLOCKS, BLOCK, 0, stream>>>(logit, target, weight, partials);
    seesaw_reduce<<<1, 1024, 0, stream>>>(partials, out);
}

// Round 9
// 16.467 us; speedup vs baseline: 4.1405x; 1.1634x over previous
//
#include <hip/hip_runtime.h>

// SeeSawLoss, simplified:
//   loss(b,h,w) = log( sum_i exp(l[b,i,h,w]) * max(w[b,i], w[b,t]) ) - log(w[b,t]) - l[b,t,h,w]
//   out = mean over all (b,h,w);  M[i,t] = (wi>wt ? wi/wt : 1) == max(wi,wt)/wt
// B=8, N=128, H=W=128.
//
// R8 falsified the VMEM-issue model (scalar/f2/f4 x 8..32 waves all ~18-20us).
// New theory: 64KB-stride columns alias one L1 set; outstanding-miss slots per
// set cap per-CU fill rate (~20 B/cy). This round: R5's exact structure with
// __builtin_nontemporal_load (MUBUF nt) on the streaming logit reads to bypass
// L1 allocation. t-gather stays cached. Two-kernel deterministic reduction.

#define B_    8
#define N_    128
#define HW_   16384              // 128*128
#define NPIX  (B_ * HW_)         // 131072
#define BLOCK 256
#define PX    64                 // pixels per block
#define OCTS  8                  // class octants
#define CPT   16                 // classes per thread
#define BLOCKS_PER_B (HW_ / PX)  // 256
#define NBLOCKS (B_ * BLOCKS_PER_B)  // 2048

using v2f = __attribute__((ext_vector_type(2))) float;

__global__ __launch_bounds__(BLOCK) void seesaw_main(
    const float* __restrict__ logit,
    const int*   __restrict__ target,
    const float* __restrict__ weight,
    float*       __restrict__ partials)
{
    __shared__ float w_s[N_];
    __shared__ float sa[OCTS][PX];
    __shared__ int   t_s[PX];

    const int tid  = threadIdx.x;
    const int b    = blockIdx.x >> 8;            // / BLOCKS_PER_B
    const int pix0 = (blockIdx.x & 255) * PX;
    const int pp   = tid & 31;                   // pixel-pair index
    const int q    = tid >> 5;                   // class octant
    const int px   = pp * 2;

    if (tid < N_) w_s[tid] = weight[b * N_ + tid];
    __syncthreads();

    const int2 t2 = *(const int2*)(target + b * HW_ + pix0 + px);
    if (q == 0) *(int2*)&t_s[px] = t2;

    const float wt0 = w_s[t2.x];
    const float wt1 = w_s[t2.y];

    const int ibase = q * CPT;
    const float* lp = logit + (size_t)(b * N_ + ibase) * HW_ + pix0 + px;

    float a0 = 0.0f, a1 = 0.0f;

    #pragma unroll
    for (int k = 0; k < CPT; ++k) {
        const v2f l = __builtin_nontemporal_load((const v2f*)(lp + (size_t)k * HW_));
        const float wi = w_s[ibase + k];
        a0 = fmaf(__expf(l.x), fmaxf(wi, wt0), a0);
        a1 = fmaf(__expf(l.y), fmaxf(wi, wt1), a1);
    }

    *(float2*)&sa[q][px] = make_float2(a0, a1);
    __syncthreads();

    float loss = 0.0f;
    if (tid < PX) {                              // wave 0: one lane per pixel
        float at = 0.0f;
        #pragma unroll
        for (int k = 0; k < OCTS; ++k) at += sa[k][tid];
        const int   t  = t_s[tid];
        const float wt = w_s[t];
        const float lt = logit[(size_t)(b * N_ + t) * HW_ + pix0 + tid];  // cached gather
        loss = __logf(at) - __logf(wt) - lt;

        #pragma unroll
        for (int o = 32; o > 0; o >>= 1) loss += __shfl_down(loss, o, 64);
    }
    if (tid == 0) partials[blockIdx.x] = loss;
}

__global__ __launch_bounds__(1024) void seesaw_reduce(
    const float* __restrict__ partials,
    float*       __restrict__ out)
{
    __shared__ float red[16];
    float s = partials[threadIdx.x] + partials[threadIdx.x + 1024];

    #pragma unroll
    for (int o = 32; o > 0; o >>= 1) s += __shfl_down(s, o, 64);

    const int lane = threadIdx.x & 63;
    const int wid  = threadIdx.x >> 6;
    if (lane == 0) red[wid] = s;
    __syncthreads();

    if (threadIdx.x == 0) {
        float tot = 0.0f;
        #pragma unroll
        for (int k = 0; k < 16; ++k) tot += red[k];
        out[0] = tot * (1.0f / (float)NPIX);
    }
}

extern "C" void kernel_launch(void* const* d_in, const int* in_sizes, int n_in,
                              void* d_out, int out_size, void* d_ws, size_t ws_size,
                              hipStream_t stream)
{
    const float* logit  = (const float*)d_in[0];
    const int*   target = (const int*)  d_in[1];
    const float* weight = (const float*)d_in[2];
    // d_in[3] = epoch (unused by the reference math)

    float* partials = (float*)d_ws;   // NBLOCKS floats
    float* out      = (float*)d_out;

    seesaw_main<<<NBLOCKS, BLOCK, 0, stream>>>(logit, target, weight, partials);
    seesaw_reduce<<<1, 1024, 0, stream>>>(partials, out);
}